// Round 6
// baseline (2771.212 us; speedup 1.0000x reference)
//
#include <hip/hip_runtime.h>
#include <math.h>
#include <float.h>

#define VOCABSZ 50000
#define EMBSZ 128
#define HIDSZ 128
#define BSZ 16
#define TENCSZ 64
#define STEPSN 24
#define STARTTOK 2

#define ROWSB 64              // vocab rows per block
#define NBLK 782              // ceil(50000/64)
#define NSLOT (NBLK*4)        // per-wave partial slots

// ws float layout
#define FEAT_OFF 0
#define HBUF_OFF (STEPSN*BSZ*256)
#define CBUF_OFF (HBUF_OFF + BSZ*HIDSZ)
#define PMAX_OFF (CBUF_OFF + STEPSN*BSZ)
#define PSUM_OFF (PMAX_OFF + NSLOT*BSZ)
#define WS_FLOATS (PSUM_OFF + NSLOT*BSZ)
// ints after floats: pidx[NSLOT*BSZ], then ctr[32]

// ---------------------------------------------------------------------------
// GRU + attention for one batch b (256-thread block).
// x-gates in registers (same thread combines); h-gates cross via s_hg[384].
// No enc LDS staging: attn loop is coalesced; score loop is 32 loads/lane.
// ---------------------------------------------------------------------------
__device__ __forceinline__ void gru_attn(
    int tid, int b, int tok, int gstep,
    const float* __restrict__ enc, const float* __restrict__ inith,
    const float* __restrict__ embed,
    const float* __restrict__ W_ih, const float* __restrict__ W_hh,
    const float* __restrict__ b_ih, const float* __restrict__ b_hh,
    float* __restrict__ ws_f,
    float* s_emb, float* s_h, float* s_hnew, float* s_hg, float* s_probs)
{
  if (tid < 128) {
    s_emb[tid] = embed[(size_t)tok * EMBSZ + tid];
    s_h[tid] = (gstep == 0) ? inith[b * HIDSZ + tid]
                            : (ws_f + HBUF_OFF)[b * HIDSZ + tid];
  }
  __syncthreads();
  float xr = 0.f, xz = 0.f, xn = 0.f;
  if (tid < 128) {
    xr = b_ih[tid]; xz = b_ih[tid + 128]; xn = b_ih[tid + 256];
    const float4* wr = (const float4*)(W_ih + (size_t)tid * EMBSZ);
    const float4* wz = (const float4*)(W_ih + (size_t)(tid + 128) * EMBSZ);
    const float4* wn = (const float4*)(W_ih + (size_t)(tid + 256) * EMBSZ);
    const float4* e4 = (const float4*)s_emb;
#pragma unroll 8
    for (int k = 0; k < 32; ++k) {
      float4 e = e4[k], a = wr[k], bq = wz[k], cq = wn[k];
      xr += a.x * e.x + a.y * e.y + a.z * e.z + a.w * e.w;
      xz += bq.x * e.x + bq.y * e.y + bq.z * e.z + bq.w * e.w;
      xn += cq.x * e.x + cq.y * e.y + cq.z * e.z + cq.w * e.w;
    }
  } else {
    int j = tid - 128;
    float hr = b_hh[j], hz = b_hh[j + 128], hn = b_hh[j + 256];
    const float4* wr = (const float4*)(W_hh + (size_t)j * HIDSZ);
    const float4* wz = (const float4*)(W_hh + (size_t)(j + 128) * HIDSZ);
    const float4* wn = (const float4*)(W_hh + (size_t)(j + 256) * HIDSZ);
    const float4* h4 = (const float4*)s_h;
    float a1 = 0.f, a2 = 0.f, a3 = 0.f;
#pragma unroll 8
    for (int k = 0; k < 32; ++k) {
      float4 h = h4[k], a = wr[k], bq = wz[k], cq = wn[k];
      a1 += a.x * h.x + a.y * h.y + a.z * h.z + a.w * h.w;
      a2 += bq.x * h.x + bq.y * h.y + bq.z * h.z + bq.w * h.w;
      a3 += cq.x * h.x + cq.y * h.y + cq.z * h.z + cq.w * h.w;
    }
    s_hg[j] = hr + a1; s_hg[128 + j] = hz + a2; s_hg[256 + j] = hn + a3;
  }
  __syncthreads();
  if (tid < 128) {
    float r = 1.f / (1.f + expf(-(xr + s_hg[tid])));
    float z = 1.f / (1.f + expf(-(xz + s_hg[128 + tid])));
    float n = tanhf(xn + r * s_hg[256 + tid]);
    s_hnew[tid] = (1.f - z) * n + z * s_h[tid];
  }
  __syncthreads();
  if (tid < 64) {
    const float4* ep = (const float4*)(enc + ((size_t)b * TENCSZ + tid) * 256);
    const float4* h4 = (const float4*)s_hnew;
    float sc = 0.f;
#pragma unroll 8
    for (int k = 0; k < 32; ++k) {
      float4 e = ep[k], h = h4[k];
      sc += e.x * h.x + e.y * h.y + e.z * h.z + e.w * h.w;
    }
    float mx = sc;
#pragma unroll
    for (int off = 32; off; off >>= 1) mx = fmaxf(mx, __shfl_xor(mx, off));
    float p = expf(sc - mx);
    float su = p;
#pragma unroll
    for (int off = 32; off; off >>= 1) su += __shfl_xor(su, off);
    s_probs[tid] = p / su;
  }
  __syncthreads();
  if (tid < 128) {
    float a = 0.f;
#pragma unroll 8
    for (int tt = 0; tt < TENCSZ; ++tt)
      a += s_probs[tt] * enc[((size_t)b * TENCSZ + tt) * 256 + tid];
    float* fptr = ws_f + FEAT_OFF + ((size_t)gstep * BSZ + b) * 256;
    fptr[tid] = a;
    fptr[128 + tid] = s_hnew[tid];
    (ws_f + HBUF_OFF)[b * HIDSZ + tid] = s_hnew[tid];
  }
}

// ---------------------------------------------------------------------------
// Step kernel: register GEMM (wave = 8 rows x 8 k-chunks, 2 rows/lane,
// 16 batches) + in-GEMM softmax partials + folded subtract of c[t-1] +
// fused epilogue: last 16 finisher blocks reduce partials and run GRU+attn.
// ---------------------------------------------------------------------------
__global__ __launch_bounds__(256) void step_kernel(
    const float* __restrict__ Wl, const float* __restrict__ bl,
    const float* __restrict__ enc, const float* __restrict__ inith,
    const float* __restrict__ embed,
    const float* __restrict__ W_ih, const float* __restrict__ W_hh,
    const float* __restrict__ b_ih, const float* __restrict__ b_hh,
    float* __restrict__ ws_f, int* __restrict__ ws_i,
    float* __restrict__ out, int t)
{
  __shared__ float s_emb[EMBSZ], s_h[HIDSZ], s_hnew[HIDSZ];
  __shared__ float s_hg[3 * HIDSZ], s_probs[TENCSZ];
  __shared__ float s_rm[4], s_rs[4]; __shared__ int s_ri[4];
  __shared__ int s_ticket; __shared__ float s_gm; __shared__ int s_gi, s_tok;

  int* pidx = ws_i;
  int* ctr = ws_i + NSLOT * BSZ;
  float* pmax = ws_f + PMAX_OFF;
  float* psum = ws_f + PSUM_OFF;

  const int tid = threadIdx.x;
  const int lane = tid & 63;
  const int w = tid >> 6;
  const int r0 = lane >> 3;
  const int c = lane & 7;
  const int v1 = blockIdx.x * ROWSB + w * 16 + r0;
  const int v2 = v1 + 8;
  const bool val1 = v1 < VOCABSZ, val2 = v2 < VOCABSZ;
  const int v1c = val1 ? v1 : 0;
  const int v2c = val2 ? v2 : 0;

  const float4* F4 = (const float4*)(ws_f + FEAT_OFF + (size_t)t * (BSZ * 256));
  const float4* W4 = (const float4*)Wl;
  const int a1 = v1c * 64 + c;
  const int a2 = v2c * 64 + c;

  float acc1[BSZ], acc2[BSZ];
#pragma unroll
  for (int b = 0; b < BSZ; ++b) { acc1[b] = 0.f; acc2[b] = 0.f; }

#pragma unroll
  for (int i = 0; i < 8; ++i) {
    float4 w1 = W4[a1 + i * 8];
    float4 w2 = W4[a2 + i * 8];
#pragma unroll
    for (int b = 0; b < BSZ; ++b) {
      float4 f = F4[b * 64 + i * 8 + c];
      acc1[b] += f.x * w1.x + f.y * w1.y + f.z * w1.z + f.w * w1.w;
      acc2[b] += f.x * w2.x + f.y * w2.y + f.z * w2.z + f.w * w2.w;
    }
  }
  // all-reduce over the 8 k-chunks (lane bits 0..2)
#pragma unroll
  for (int off = 1; off <= 4; off <<= 1) {
#pragma unroll
    for (int b = 0; b < BSZ; ++b) {
      acc1[b] += __shfl_xor(acc1[b], off);
      acc2[b] += __shfl_xor(acc2[b], off);
    }
  }
  const float lb1 = bl[v1c], lb2 = bl[v2c];
  const float* cb = ws_f + CBUF_OFF + (t - 1) * BSZ;
  const int slot = blockIdx.x * 4 + w;

#pragma unroll
  for (int b = 0; b < BSZ; ++b) {
    float lg1 = acc1[b] + lb1;
    float lg2 = acc2[b] + lb2;
    if ((b & 7) == c) {
      if (val1) out[((size_t)t * BSZ + b) * VOCABSZ + v1] = lg1;
      if (val2) out[((size_t)t * BSZ + b) * VOCABSZ + v2] = lg2;
      if (t > 0) {
        float cv = cb[b];
        if (val1) { size_t i1 = ((size_t)(t - 1) * BSZ + b) * VOCABSZ + v1; out[i1] -= cv; }
        if (val2) { size_t i2 = ((size_t)(t - 1) * BSZ + b) * VOCABSZ + v2; out[i2] -= cv; }
      }
    }
    // wave partial (16 rows): max/argmax with lowest-index tie-break, sum-exp
    float m; int mi;
    if (val1) { m = lg1; mi = v1; } else { m = -FLT_MAX; mi = 0x7fffffff; }
    if (val2 && lg2 > m) { m = lg2; mi = v2; }
#pragma unroll
    for (int off = 8; off <= 32; off <<= 1) {
      float om = __shfl_xor(m, off); int oi = __shfl_xor(mi, off);
      if (om > m || (om == m && oi < mi)) { m = om; mi = oi; }
    }
    float s = (val1 ? __expf(lg1 - m) : 0.f) + (val2 ? __expf(lg2 - m) : 0.f);
#pragma unroll
    for (int off = 8; off <= 32; off <<= 1) s += __shfl_xor(s, off);
    if (lane == b) {
      pmax[b * NSLOT + slot] = m;
      psum[b * NSLOT + slot] = s;
      pidx[b * NSLOT + slot] = mi;
    }
  }

  // ---- handshake: release ticket; last 16 arrivals become finishers ----
  __syncthreads();   // drains all threads' stores (vmcnt 0) before publish
  if (tid == 0)
    s_ticket = __hip_atomic_fetch_add(ctr + t, 1, __ATOMIC_RELEASE,
                                      __HIP_MEMORY_SCOPE_AGENT);
  __syncthreads();
  const int ticket = s_ticket;
  if (ticket < NBLK - BSZ) return;
  const int b = ticket - (NBLK - BSZ);

  if (tid == 0) {
    while (__hip_atomic_load(ctr + t, __ATOMIC_ACQUIRE,
                             __HIP_MEMORY_SCOPE_AGENT) < NBLK)
      __builtin_amdgcn_s_sleep(2);
  }
  __syncthreads();

  // ---- reduce 3128 partials for batch b ----
  float m = -FLT_MAX; int mi = 0x7fffffff;
  for (int i = tid; i < NSLOT; i += 256) {
    float mm = pmax[b * NSLOT + i]; int ii = pidx[b * NSLOT + i];
    if (mm > m || (mm == m && ii < mi)) { m = mm; mi = ii; }
  }
#pragma unroll
  for (int off = 32; off; off >>= 1) {
    float om = __shfl_xor(m, off); int oi = __shfl_xor(mi, off);
    if (om > m || (om == m && oi < mi)) { m = om; mi = oi; }
  }
  if (lane == 0) { s_rm[w] = m; s_ri[w] = mi; }
  __syncthreads();
  if (tid == 0) {
    float gm = s_rm[0]; int gi = s_ri[0];
#pragma unroll
    for (int q = 1; q < 4; ++q)
      if (s_rm[q] > gm || (s_rm[q] == gm && s_ri[q] < gi)) { gm = s_rm[q]; gi = s_ri[q]; }
    s_gm = gm; s_gi = gi;
  }
  __syncthreads();
  const float gm = s_gm;

  float s = 0.f;
  for (int i = tid; i < NSLOT; i += 256)
    s += psum[b * NSLOT + i] * __expf(pmax[b * NSLOT + i] - gm);
#pragma unroll
  for (int off = 32; off; off >>= 1) s += __shfl_xor(s, off);
  if (lane == 0) s_rs[w] = s;
  __syncthreads();
  if (tid == 0) {
    float tot = s_rs[0] + s_rs[1] + s_rs[2] + s_rs[3];
    (ws_f + CBUF_OFF)[t * BSZ + b] = gm + logf(tot);
    out[(size_t)STEPSN * BSZ * VOCABSZ + t * BSZ + b] = (float)s_gi;
    s_tok = s_gi;
  }
  __syncthreads();

  if (t < STEPSN - 1) {
    gru_attn(tid, b, s_tok, t + 1, enc, inith, embed, W_ih, W_hh, b_ih, b_hh,
             ws_f, s_emb, s_h, s_hnew, s_hg, s_probs);
  }
}

// ---------------------------------------------------------------------------
// feat0: zero ctr (block 0) + GRU+attn for step 0. grid = 16.
// ---------------------------------------------------------------------------
__global__ __launch_bounds__(256) void feat0_kernel(
    const float* __restrict__ enc, const float* __restrict__ inith,
    const float* __restrict__ embed,
    const float* __restrict__ W_ih, const float* __restrict__ W_hh,
    const float* __restrict__ b_ih, const float* __restrict__ b_hh,
    float* __restrict__ ws_f, int* __restrict__ ws_i)
{
  __shared__ float s_emb[EMBSZ], s_h[HIDSZ], s_hnew[HIDSZ];
  __shared__ float s_hg[3 * HIDSZ], s_probs[TENCSZ];
  if (blockIdx.x == 0 && threadIdx.x < 32)
    (ws_i + NSLOT * BSZ)[threadIdx.x] = 0;
  gru_attn(threadIdx.x, blockIdx.x, STARTTOK, 0, enc, inith, embed,
           W_ih, W_hh, b_ih, b_hh, ws_f, s_emb, s_h, s_hnew, s_hg, s_probs);
}

// ---------------------------------------------------------------------------
// Last-step subtract: out[23,b,v] -= c[23,b].
// ---------------------------------------------------------------------------
__global__ __launch_bounds__(256) void sub_last_kernel(
    const float* __restrict__ cbuf, float* __restrict__ out)
{
  size_t i = ((size_t)blockIdx.x * 256 + threadIdx.x) * 8;
  if (i >= (size_t)BSZ * VOCABSZ) return;
  int b = (int)(i / VOCABSZ);
  float cv = cbuf[(STEPSN - 1) * BSZ + b];
  float4* p = (float4*)(out + (size_t)(STEPSN - 1) * BSZ * VOCABSZ + i);
  float4 x0 = p[0], x1 = p[1];
  x0.x -= cv; x0.y -= cv; x0.z -= cv; x0.w -= cv;
  x1.x -= cv; x1.y -= cv; x1.z -= cv; x1.w -= cv;
  p[0] = x0; p[1] = x1;
}

extern "C" void kernel_launch(void* const* d_in, const int* in_sizes, int n_in,
                              void* d_out, int out_size, void* d_ws, size_t ws_size,
                              hipStream_t stream)
{
  const float* enc   = (const float*)d_in[0];
  const float* inith = (const float*)d_in[1];
  const float* embed = (const float*)d_in[2];
  const float* W_ih  = (const float*)d_in[3];
  const float* W_hh  = (const float*)d_in[4];
  const float* b_ih  = (const float*)d_in[5];
  const float* b_hh  = (const float*)d_in[6];
  const float* Wl    = (const float*)d_in[7];
  const float* bl    = (const float*)d_in[8];
  float* out = (float*)d_out;

  float* ws_f = (float*)d_ws;
  int* ws_i = (int*)(ws_f + WS_FLOATS);

  feat0_kernel<<<BSZ, 256, 0, stream>>>(enc, inith, embed, W_ih, W_hh,
                                        b_ih, b_hh, ws_f, ws_i);
  for (int t = 0; t < STEPSN; ++t) {
    step_kernel<<<NBLK, 256, 0, stream>>>(Wl, bl, enc, inith, embed,
                                          W_ih, W_hh, b_ih, b_hh,
                                          ws_f, ws_i, out, t);
  }
  const int nsub = (BSZ * VOCABSZ / 8 + 255) / 256;
  sub_last_kernel<<<nsub, 256, 0, stream>>>(ws_f + CBUF_OFF, out);
}

// Round 7
// 2549.350 us; speedup vs baseline: 1.0870x; 1.0870x over previous
//
#include <hip/hip_runtime.h>
#include <math.h>
#include <float.h>

#define VOCABSZ 50000
#define EMBSZ 128
#define HIDSZ 128
#define BSZ 16
#define TENCSZ 64
#define STEPSN 24
#define STARTTOK 2

#define ROWSB 64              // vocab rows per block
#define NBLK 782              // ceil(50000/64)
#define NSLOT (NBLK*4)        // per-wave partial slots

// ws float layout
#define FEAT_OFF 0
#define HBUF_OFF (STEPSN*BSZ*256)
#define CBUF_OFF (HBUF_OFF + BSZ*HIDSZ)
#define PMAX_OFF (CBUF_OFF + STEPSN*BSZ)
#define PSUM_OFF (PMAX_OFF + NSLOT*BSZ)
#define WS_FLOATS (PSUM_OFF + NSLOT*BSZ)
// ints after floats: pidx[NSLOT*BSZ], then ctr[32]

#define ATOMIC_STF(p, v) __hip_atomic_store((p), (v), __ATOMIC_RELAXED, __HIP_MEMORY_SCOPE_AGENT)
#define ATOMIC_LDF(p)    __hip_atomic_load((p), __ATOMIC_RELAXED, __HIP_MEMORY_SCOPE_AGENT)

// ---------------------------------------------------------------------------
// GRU + attention for one batch b (256-thread block).
// ---------------------------------------------------------------------------
__device__ __forceinline__ void gru_attn(
    int tid, int b, int tok, int gstep,
    const float* __restrict__ enc, const float* __restrict__ inith,
    const float* __restrict__ embed,
    const float* __restrict__ W_ih, const float* __restrict__ W_hh,
    const float* __restrict__ b_ih, const float* __restrict__ b_hh,
    float* __restrict__ ws_f,
    float* s_emb, float* s_h, float* s_hnew, float* s_hg, float* s_probs)
{
  if (tid < 128) {
    s_emb[tid] = embed[(size_t)tok * EMBSZ + tid];
    s_h[tid] = (gstep == 0) ? inith[b * HIDSZ + tid]
                            : (ws_f + HBUF_OFF)[b * HIDSZ + tid];
  }
  __syncthreads();
  float xr = 0.f, xz = 0.f, xn = 0.f;
  if (tid < 128) {
    xr = b_ih[tid]; xz = b_ih[tid + 128]; xn = b_ih[tid + 256];
    const float4* wr = (const float4*)(W_ih + (size_t)tid * EMBSZ);
    const float4* wz = (const float4*)(W_ih + (size_t)(tid + 128) * EMBSZ);
    const float4* wn = (const float4*)(W_ih + (size_t)(tid + 256) * EMBSZ);
    const float4* e4 = (const float4*)s_emb;
#pragma unroll 8
    for (int k = 0; k < 32; ++k) {
      float4 e = e4[k], a = wr[k], bq = wz[k], cq = wn[k];
      xr += a.x * e.x + a.y * e.y + a.z * e.z + a.w * e.w;
      xz += bq.x * e.x + bq.y * e.y + bq.z * e.z + bq.w * e.w;
      xn += cq.x * e.x + cq.y * e.y + cq.z * e.z + cq.w * e.w;
    }
  } else {
    int j = tid - 128;
    float hr = b_hh[j], hz = b_hh[j + 128], hn = b_hh[j + 256];
    const float4* wr = (const float4*)(W_hh + (size_t)j * HIDSZ);
    const float4* wz = (const float4*)(W_hh + (size_t)(j + 128) * HIDSZ);
    const float4* wn = (const float4*)(W_hh + (size_t)(j + 256) * HIDSZ);
    const float4* h4 = (const float4*)s_h;
    float a1 = 0.f, a2 = 0.f, a3 = 0.f;
#pragma unroll 8
    for (int k = 0; k < 32; ++k) {
      float4 h = h4[k], a = wr[k], bq = wz[k], cq = wn[k];
      a1 += a.x * h.x + a.y * h.y + a.z * h.z + a.w * h.w;
      a2 += bq.x * h.x + bq.y * h.y + bq.z * h.z + bq.w * h.w;
      a3 += cq.x * h.x + cq.y * h.y + cq.z * h.z + cq.w * h.w;
    }
    s_hg[j] = hr + a1; s_hg[128 + j] = hz + a2; s_hg[256 + j] = hn + a3;
  }
  __syncthreads();
  if (tid < 128) {
    float r = 1.f / (1.f + expf(-(xr + s_hg[tid])));
    float z = 1.f / (1.f + expf(-(xz + s_hg[128 + tid])));
    float n = tanhf(xn + r * s_hg[256 + tid]);
    s_hnew[tid] = (1.f - z) * n + z * s_h[tid];
  }
  __syncthreads();
  if (tid < 64) {
    const float4* ep = (const float4*)(enc + ((size_t)b * TENCSZ + tid) * 256);
    const float4* h4 = (const float4*)s_hnew;
    float sc = 0.f;
#pragma unroll 8
    for (int k = 0; k < 32; ++k) {
      float4 e = ep[k], h = h4[k];
      sc += e.x * h.x + e.y * h.y + e.z * h.z + e.w * h.w;
    }
    float mx = sc;
#pragma unroll
    for (int off = 32; off; off >>= 1) mx = fmaxf(mx, __shfl_xor(mx, off));
    float p = expf(sc - mx);
    float su = p;
#pragma unroll
    for (int off = 32; off; off >>= 1) su += __shfl_xor(su, off);
    s_probs[tid] = p / su;
  }
  __syncthreads();
  if (tid < 128) {
    float a = 0.f;
#pragma unroll 8
    for (int tt = 0; tt < TENCSZ; ++tt)
      a += s_probs[tt] * enc[((size_t)b * TENCSZ + tt) * 256 + tid];
    float* fptr = ws_f + FEAT_OFF + ((size_t)gstep * BSZ + b) * 256;
    fptr[tid] = a;
    fptr[128 + tid] = s_hnew[tid];
    (ws_f + HBUF_OFF)[b * HIDSZ + tid] = s_hnew[tid];
  }
}

// ---------------------------------------------------------------------------
// Step kernel: register GEMM + in-GEMM softmax partials + folded subtract +
// fused epilogue via RELAXED-atomic handshake (no L2 flush/invalidate).
// ---------------------------------------------------------------------------
__global__ __launch_bounds__(256) void step_kernel(
    const float* __restrict__ Wl, const float* __restrict__ bl,
    const float* __restrict__ enc, const float* __restrict__ inith,
    const float* __restrict__ embed,
    const float* __restrict__ W_ih, const float* __restrict__ W_hh,
    const float* __restrict__ b_ih, const float* __restrict__ b_hh,
    float* __restrict__ ws_f, int* __restrict__ ws_i,
    float* __restrict__ out, int t)
{
  __shared__ float s_emb[EMBSZ], s_h[HIDSZ], s_hnew[HIDSZ];
  __shared__ float s_hg[3 * HIDSZ], s_probs[TENCSZ];
  __shared__ float s_rm[4], s_rs[4]; __shared__ int s_ri[4];
  __shared__ int s_ticket; __shared__ float s_gm; __shared__ int s_gi, s_tok;

  int* pidx = ws_i;
  int* ctr = ws_i + NSLOT * BSZ;
  float* pmax = ws_f + PMAX_OFF;
  float* psum = ws_f + PSUM_OFF;

  const int tid = threadIdx.x;
  const int lane = tid & 63;
  const int w = tid >> 6;
  const int r0 = lane >> 3;
  const int c = lane & 7;
  const int v1 = blockIdx.x * ROWSB + w * 16 + r0;
  const int v2 = v1 + 8;
  const bool val1 = v1 < VOCABSZ, val2 = v2 < VOCABSZ;
  const int v1c = val1 ? v1 : 0;
  const int v2c = val2 ? v2 : 0;

  const float4* F4 = (const float4*)(ws_f + FEAT_OFF + (size_t)t * (BSZ * 256));
  const float4* W4 = (const float4*)Wl;
  const int a1 = v1c * 64 + c;
  const int a2 = v2c * 64 + c;

  float acc1[BSZ], acc2[BSZ];
#pragma unroll
  for (int b = 0; b < BSZ; ++b) { acc1[b] = 0.f; acc2[b] = 0.f; }

#pragma unroll
  for (int i = 0; i < 8; ++i) {
    float4 w1 = W4[a1 + i * 8];
    float4 w2 = W4[a2 + i * 8];
#pragma unroll
    for (int b = 0; b < BSZ; ++b) {
      float4 f = F4[b * 64 + i * 8 + c];
      acc1[b] += f.x * w1.x + f.y * w1.y + f.z * w1.z + f.w * w1.w;
      acc2[b] += f.x * w2.x + f.y * w2.y + f.z * w2.z + f.w * w2.w;
    }
  }
  // all-reduce over the 8 k-chunks (lane bits 0..2)
#pragma unroll
  for (int off = 1; off <= 4; off <<= 1) {
#pragma unroll
    for (int b = 0; b < BSZ; ++b) {
      acc1[b] += __shfl_xor(acc1[b], off);
      acc2[b] += __shfl_xor(acc2[b], off);
    }
  }
  const float lb1 = bl[v1c], lb2 = bl[v2c];
  const float* cb = ws_f + CBUF_OFF + (t - 1) * BSZ;
  const int slot = blockIdx.x * 4 + w;

#pragma unroll
  for (int b = 0; b < BSZ; ++b) {
    float lg1 = acc1[b] + lb1;
    float lg2 = acc2[b] + lb2;
    if ((b & 7) == c) {
      if (val1) out[((size_t)t * BSZ + b) * VOCABSZ + v1] = lg1;
      if (val2) out[((size_t)t * BSZ + b) * VOCABSZ + v2] = lg2;
      if (t > 0) {
        float cv = cb[b];
        if (val1) { size_t i1 = ((size_t)(t - 1) * BSZ + b) * VOCABSZ + v1; out[i1] -= cv; }
        if (val2) { size_t i2 = ((size_t)(t - 1) * BSZ + b) * VOCABSZ + v2; out[i2] -= cv; }
      }
    }
    // wave partial (16 rows): max/argmax with lowest-index tie-break, sum-exp
    float m; int mi;
    if (val1) { m = lg1; mi = v1; } else { m = -FLT_MAX; mi = 0x7fffffff; }
    if (val2 && lg2 > m) { m = lg2; mi = v2; }
#pragma unroll
    for (int off = 8; off <= 32; off <<= 1) {
      float om = __shfl_xor(m, off); int oi = __shfl_xor(mi, off);
      if (om > m || (om == m && oi < mi)) { m = om; mi = oi; }
    }
    float s = (val1 ? __expf(lg1 - m) : 0.f) + (val2 ? __expf(lg2 - m) : 0.f);
#pragma unroll
    for (int off = 8; off <= 32; off <<= 1) s += __shfl_xor(s, off);
    if (lane == b) {
      ATOMIC_STF(&pmax[b * NSLOT + slot], m);
      ATOMIC_STF(&psum[b * NSLOT + slot], s);
      __hip_atomic_store(&pidx[b * NSLOT + slot], mi, __ATOMIC_RELAXED,
                         __HIP_MEMORY_SCOPE_AGENT);
    }
  }

  // ---- handshake: relaxed ticket; last 16 arrivals become finishers ----
  // Order: every thread drains its own VMEM stores, block-barrier, then the
  // ticket add. No acquire/release -> no L2 writeback/invalidate storm.
  asm volatile("s_waitcnt vmcnt(0)" ::: "memory");
  __syncthreads();
  if (tid == 0)
    s_ticket = __hip_atomic_fetch_add(ctr + t, 1, __ATOMIC_RELAXED,
                                      __HIP_MEMORY_SCOPE_AGENT);
  __syncthreads();
  const int ticket = s_ticket;
  if (ticket < NBLK - BSZ) return;
  const int b = ticket - (NBLK - BSZ);

  if (tid == 0) {
    while (__hip_atomic_load(ctr + t, __ATOMIC_RELAXED,
                             __HIP_MEMORY_SCOPE_AGENT) < NBLK)
      __builtin_amdgcn_s_sleep(8);
  }
  __syncthreads();

  // ---- reduce 3128 partials for batch b (relaxed atomic loads: coherent) ----
  float m = -FLT_MAX; int mi = 0x7fffffff;
  for (int i = tid; i < NSLOT; i += 256) {
    float mm = ATOMIC_LDF(&pmax[b * NSLOT + i]);
    int ii = __hip_atomic_load(&pidx[b * NSLOT + i], __ATOMIC_RELAXED,
                               __HIP_MEMORY_SCOPE_AGENT);
    if (mm > m || (mm == m && ii < mi)) { m = mm; mi = ii; }
  }
#pragma unroll
  for (int off = 32; off; off >>= 1) {
    float om = __shfl_xor(m, off); int oi = __shfl_xor(mi, off);
    if (om > m || (om == m && oi < mi)) { m = om; mi = oi; }
  }
  if (lane == 0) { s_rm[w] = m; s_ri[w] = mi; }
  __syncthreads();
  if (tid == 0) {
    float gm = s_rm[0]; int gi = s_ri[0];
#pragma unroll
    for (int q = 1; q < 4; ++q)
      if (s_rm[q] > gm || (s_rm[q] == gm && s_ri[q] < gi)) { gm = s_rm[q]; gi = s_ri[q]; }
    s_gm = gm; s_gi = gi;
  }
  __syncthreads();
  const float gm = s_gm;

  float s = 0.f;
  for (int i = tid; i < NSLOT; i += 256)
    s += ATOMIC_LDF(&psum[b * NSLOT + i]) * __expf(ATOMIC_LDF(&pmax[b * NSLOT + i]) - gm);
#pragma unroll
  for (int off = 32; off; off >>= 1) s += __shfl_xor(s, off);
  if (lane == 0) s_rs[w] = s;
  __syncthreads();
  if (tid == 0) {
    float tot = s_rs[0] + s_rs[1] + s_rs[2] + s_rs[3];
    (ws_f + CBUF_OFF)[t * BSZ + b] = gm + logf(tot);
    out[(size_t)STEPSN * BSZ * VOCABSZ + t * BSZ + b] = (float)s_gi;
    s_tok = s_gi;
  }
  __syncthreads();

  if (t < STEPSN - 1) {
    gru_attn(tid, b, s_tok, t + 1, enc, inith, embed, W_ih, W_hh, b_ih, b_hh,
             ws_f, s_emb, s_h, s_hnew, s_hg, s_probs);
  }
}

// ---------------------------------------------------------------------------
// feat0: zero ctr (block 0) + GRU+attn for step 0. grid = 16.
// ---------------------------------------------------------------------------
__global__ __launch_bounds__(256) void feat0_kernel(
    const float* __restrict__ enc, const float* __restrict__ inith,
    const float* __restrict__ embed,
    const float* __restrict__ W_ih, const float* __restrict__ W_hh,
    const float* __restrict__ b_ih, const float* __restrict__ b_hh,
    float* __restrict__ ws_f, int* __restrict__ ws_i)
{
  __shared__ float s_emb[EMBSZ], s_h[HIDSZ], s_hnew[HIDSZ];
  __shared__ float s_hg[3 * HIDSZ], s_probs[TENCSZ];
  if (blockIdx.x == 0 && threadIdx.x < 32)
    (ws_i + NSLOT * BSZ)[threadIdx.x] = 0;
  gru_attn(threadIdx.x, blockIdx.x, STARTTOK, 0, enc, inith, embed,
           W_ih, W_hh, b_ih, b_hh, ws_f, s_emb, s_h, s_hnew, s_hg, s_probs);
}

// ---------------------------------------------------------------------------
// Last-step subtract: out[23,b,v] -= c[23,b].
// ---------------------------------------------------------------------------
__global__ __launch_bounds__(256) void sub_last_kernel(
    const float* __restrict__ cbuf, float* __restrict__ out)
{
  size_t i = ((size_t)blockIdx.x * 256 + threadIdx.x) * 8;
  if (i >= (size_t)BSZ * VOCABSZ) return;
  int b = (int)(i / VOCABSZ);
  float cv = cbuf[(STEPSN - 1) * BSZ + b];
  float4* p = (float4*)(out + (size_t)(STEPSN - 1) * BSZ * VOCABSZ + i);
  float4 x0 = p[0], x1 = p[1];
  x0.x -= cv; x0.y -= cv; x0.z -= cv; x0.w -= cv;
  x1.x -= cv; x1.y -= cv; x1.z -= cv; x1.w -= cv;
  p[0] = x0; p[1] = x1;
}

extern "C" void kernel_launch(void* const* d_in, const int* in_sizes, int n_in,
                              void* d_out, int out_size, void* d_ws, size_t ws_size,
                              hipStream_t stream)
{
  const float* enc   = (const float*)d_in[0];
  const float* inith = (const float*)d_in[1];
  const float* embed = (const float*)d_in[2];
  const float* W_ih  = (const float*)d_in[3];
  const float* W_hh  = (const float*)d_in[4];
  const float* b_ih  = (const float*)d_in[5];
  const float* b_hh  = (const float*)d_in[6];
  const float* Wl    = (const float*)d_in[7];
  const float* bl    = (const float*)d_in[8];
  float* out = (float*)d_out;

  float* ws_f = (float*)d_ws;
  int* ws_i = (int*)(ws_f + WS_FLOATS);

  feat0_kernel<<<BSZ, 256, 0, stream>>>(enc, inith, embed, W_ih, W_hh,
                                        b_ih, b_hh, ws_f, ws_i);
  for (int t = 0; t < STEPSN; ++t) {
    step_kernel<<<NBLK, 256, 0, stream>>>(Wl, bl, enc, inith, embed,
                                          W_ih, W_hh, b_ih, b_hh,
                                          ws_f, ws_i, out, t);
  }
  const int nsub = (BSZ * VOCABSZ / 8 + 255) / 256;
  sub_last_kernel<<<nsub, 256, 0, stream>>>(ws_f + CBUF_OFF, out);
}

// Round 8
// 1833.740 us; speedup vs baseline: 1.5112x; 1.3902x over previous
//
#include <hip/hip_runtime.h>
#include <math.h>
#include <float.h>

#define VOCABSZ 50000
#define EMBSZ 128
#define HIDSZ 128
#define BSZ 16
#define TENCSZ 64
#define STEPSN 24
#define STARTTOK 2

#define ROWSB 64              // vocab rows per block
#define NBLK 782              // ceil(50000/64)
#define NSLOT (NBLK*4)        // per-wave partial slots

// ws float layout
#define FEAT_OFF 0
#define HBUF_OFF (STEPSN*BSZ*256)
#define CBUF_OFF (HBUF_OFF + BSZ*HIDSZ)
#define PMAX_OFF (CBUF_OFF + STEPSN*BSZ)
#define PSUM_OFF (PMAX_OFF + NSLOT*BSZ)
#define WS_FLOATS (PSUM_OFF + NSLOT*BSZ)
// ints after floats: pidx[NSLOT*BSZ]

// ---------------------------------------------------------------------------
// Step kernel v8: register GEMM with max ILP.
// wave w: 16 rows (v1=blk*64+w*16+r0, v2=v1+8), lane = r0*8+c owns k-chunk c.
// ALL 16 W float4s preloaded into registers up front (one latency exposure),
// then 128 feat loads (L2-hot, 16KB shared by all blocks) pipelined against
// 1024 FMAs. launch_bounds(256,3): 12 waves/CU, VGPR cap ~168.
// Writes logits to out[t], folds subtract of c[t-1], plain-stores partials.
// ---------------------------------------------------------------------------
__global__ __launch_bounds__(256, 3) void step_kernel(
    const float* __restrict__ Wl, const float* __restrict__ bl,
    const float* __restrict__ ws_c, float* __restrict__ ws_f,
    int* __restrict__ ws_i, float* __restrict__ out, int t)
{
  int* pidx = ws_i;
  float* pmax = ws_f + PMAX_OFF;
  float* psum = ws_f + PSUM_OFF;

  const int tid = threadIdx.x;
  const int lane = tid & 63;
  const int w = tid >> 6;
  const int r0 = lane >> 3;
  const int c = lane & 7;
  const int v1 = blockIdx.x * ROWSB + w * 16 + r0;
  const int v2 = v1 + 8;
  const bool val1 = v1 < VOCABSZ, val2 = v2 < VOCABSZ;
  const int v1c = val1 ? v1 : 0;
  const int v2c = val2 ? v2 : 0;

  const float4* __restrict__ F4 =
      (const float4*)(ws_c + FEAT_OFF + (size_t)t * (BSZ * 256));
  const float4* __restrict__ W4 = (const float4*)Wl;
  const int a1 = v1c * 64 + c;
  const int a2 = v2c * 64 + c;

  // ---- preload full W slice: 16 float4 in flight at once ----
  float4 W1[8], W2[8];
#pragma unroll
  for (int i = 0; i < 8; ++i) W1[i] = W4[a1 + i * 8];
#pragma unroll
  for (int i = 0; i < 8; ++i) W2[i] = W4[a2 + i * 8];

  float acc1[BSZ], acc2[BSZ];
#pragma unroll
  for (int b = 0; b < BSZ; ++b) { acc1[b] = 0.f; acc2[b] = 0.f; }

  // ---- FMA loop: per b, 8 feat loads pipelined against 64 FMAs ----
#pragma unroll
  for (int b = 0; b < BSZ; ++b) {
    float4 f[8];
#pragma unroll
    for (int i = 0; i < 8; ++i) f[i] = F4[b * 64 + i * 8 + c];
    float s1 = 0.f, s2 = 0.f;
#pragma unroll
    for (int i = 0; i < 8; ++i) {
      s1 += f[i].x * W1[i].x + f[i].y * W1[i].y + f[i].z * W1[i].z + f[i].w * W1[i].w;
      s2 += f[i].x * W2[i].x + f[i].y * W2[i].y + f[i].z * W2[i].z + f[i].w * W2[i].w;
    }
    acc1[b] = s1; acc2[b] = s2;
  }

  // all-reduce over the 8 k-chunks (lane bits 0..2)
#pragma unroll
  for (int off = 1; off <= 4; off <<= 1) {
#pragma unroll
    for (int b = 0; b < BSZ; ++b) {
      acc1[b] += __shfl_xor(acc1[b], off);
      acc2[b] += __shfl_xor(acc2[b], off);
    }
  }
  const float lb1 = bl[v1c], lb2 = bl[v2c];
  const float* cb = ws_c + CBUF_OFF + (t - 1) * BSZ;
  const int slot = blockIdx.x * 4 + w;

#pragma unroll
  for (int b = 0; b < BSZ; ++b) {
    float lg1 = acc1[b] + lb1;
    float lg2 = acc2[b] + lb2;
    if ((b & 7) == c) {
      if (val1) out[((size_t)t * BSZ + b) * VOCABSZ + v1] = lg1;
      if (val2) out[((size_t)t * BSZ + b) * VOCABSZ + v2] = lg2;
      if (t > 0) {
        float cv = cb[b];
        if (val1) { size_t i1 = ((size_t)(t - 1) * BSZ + b) * VOCABSZ + v1; out[i1] -= cv; }
        if (val2) { size_t i2 = ((size_t)(t - 1) * BSZ + b) * VOCABSZ + v2; out[i2] -= cv; }
      }
    }
    // wave partial (16 rows): max/argmax with lowest-index tie-break, sum-exp
    float m; int mi;
    if (val1) { m = lg1; mi = v1; } else { m = -FLT_MAX; mi = 0x7fffffff; }
    if (val2 && lg2 > m) { m = lg2; mi = v2; }
#pragma unroll
    for (int off = 8; off <= 32; off <<= 1) {
      float om = __shfl_xor(m, off); int oi = __shfl_xor(mi, off);
      if (om > m || (om == m && oi < mi)) { m = om; mi = oi; }
    }
    float s = (val1 ? __expf(lg1 - m) : 0.f) + (val2 ? __expf(lg2 - m) : 0.f);
#pragma unroll
    for (int off = 8; off <= 32; off <<= 1) s += __shfl_xor(s, off);
    if (lane == b) {
      pmax[b * NSLOT + slot] = m;
      psum[b * NSLOT + slot] = s;
      pidx[b * NSLOT + slot] = mi;
    }
  }
}

// ---------------------------------------------------------------------------
// GRU + attention for one batch b (256-thread block).
// ---------------------------------------------------------------------------
__device__ __forceinline__ void gru_attn(
    int tid, int b, int tok, int gstep,
    const float* __restrict__ enc, const float* __restrict__ inith,
    const float* __restrict__ embed,
    const float* __restrict__ W_ih, const float* __restrict__ W_hh,
    const float* __restrict__ b_ih, const float* __restrict__ b_hh,
    float* __restrict__ ws_f,
    float* s_emb, float* s_h, float* s_hnew, float* s_hg, float* s_probs)
{
  if (tid < 128) {
    s_emb[tid] = embed[(size_t)tok * EMBSZ + tid];
    s_h[tid] = (gstep == 0) ? inith[b * HIDSZ + tid]
                            : (ws_f + HBUF_OFF)[b * HIDSZ + tid];
  }
  __syncthreads();
  float xr = 0.f, xz = 0.f, xn = 0.f;
  if (tid < 128) {
    xr = b_ih[tid]; xz = b_ih[tid + 128]; xn = b_ih[tid + 256];
    const float4* wr = (const float4*)(W_ih + (size_t)tid * EMBSZ);
    const float4* wz = (const float4*)(W_ih + (size_t)(tid + 128) * EMBSZ);
    const float4* wn = (const float4*)(W_ih + (size_t)(tid + 256) * EMBSZ);
    const float4* e4 = (const float4*)s_emb;
#pragma unroll 8
    for (int k = 0; k < 32; ++k) {
      float4 e = e4[k], a = wr[k], bq = wz[k], cq = wn[k];
      xr += a.x * e.x + a.y * e.y + a.z * e.z + a.w * e.w;
      xz += bq.x * e.x + bq.y * e.y + bq.z * e.z + bq.w * e.w;
      xn += cq.x * e.x + cq.y * e.y + cq.z * e.z + cq.w * e.w;
    }
  } else {
    int j = tid - 128;
    float hr = b_hh[j], hz = b_hh[j + 128], hn = b_hh[j + 256];
    const float4* wr = (const float4*)(W_hh + (size_t)j * HIDSZ);
    const float4* wz = (const float4*)(W_hh + (size_t)(j + 128) * HIDSZ);
    const float4* wn = (const float4*)(W_hh + (size_t)(j + 256) * HIDSZ);
    const float4* h4 = (const float4*)s_h;
    float a1 = 0.f, a2 = 0.f, a3 = 0.f;
#pragma unroll 8
    for (int k = 0; k < 32; ++k) {
      float4 h = h4[k], a = wr[k], bq = wz[k], cq = wn[k];
      a1 += a.x * h.x + a.y * h.y + a.z * h.z + a.w * h.w;
      a2 += bq.x * h.x + bq.y * h.y + bq.z * h.z + bq.w * h.w;
      a3 += cq.x * h.x + cq.y * h.y + cq.z * h.z + cq.w * h.w;
    }
    s_hg[j] = hr + a1; s_hg[128 + j] = hz + a2; s_hg[256 + j] = hn + a3;
  }
  __syncthreads();
  if (tid < 128) {
    float r = 1.f / (1.f + expf(-(xr + s_hg[tid])));
    float z = 1.f / (1.f + expf(-(xz + s_hg[128 + tid])));
    float n = tanhf(xn + r * s_hg[256 + tid]);
    s_hnew[tid] = (1.f - z) * n + z * s_h[tid];
  }
  __syncthreads();
  if (tid < 64) {
    const float4* ep = (const float4*)(enc + ((size_t)b * TENCSZ + tid) * 256);
    const float4* h4 = (const float4*)s_hnew;
    float sc = 0.f;
#pragma unroll 8
    for (int k = 0; k < 32; ++k) {
      float4 e = ep[k], h = h4[k];
      sc += e.x * h.x + e.y * h.y + e.z * h.z + e.w * h.w;
    }
    float mx = sc;
#pragma unroll
    for (int off = 32; off; off >>= 1) mx = fmaxf(mx, __shfl_xor(mx, off));
    float p = expf(sc - mx);
    float su = p;
#pragma unroll
    for (int off = 32; off; off >>= 1) su += __shfl_xor(su, off);
    s_probs[tid] = p / su;
  }
  __syncthreads();
  if (tid < 128) {
    float a = 0.f;
#pragma unroll 8
    for (int tt = 0; tt < TENCSZ; ++tt)
      a += s_probs[tt] * enc[((size_t)b * TENCSZ + tt) * 256 + tid];
    float* fptr = ws_f + FEAT_OFF + ((size_t)gstep * BSZ + b) * 256;
    fptr[tid] = a;
    fptr[128 + tid] = s_hnew[tid];
    (ws_f + HBUF_OFF)[b * HIDSZ + tid] = s_hnew[tid];
  }
}

// ---------------------------------------------------------------------------
// rg kernel: reduce step rstep's partials -> {c, token}, then GRU+attention
// for step gstep -> feat[gstep], h.  grid = 16 blocks (one per batch).
// ---------------------------------------------------------------------------
__global__ __launch_bounds__(256) void rg_kernel(
    const float* __restrict__ enc, const float* __restrict__ inith,
    const float* __restrict__ embed,
    const float* __restrict__ W_ih, const float* __restrict__ W_hh,
    const float* __restrict__ b_ih, const float* __restrict__ b_hh,
    float* __restrict__ ws_f, int* __restrict__ ws_i,
    float* __restrict__ out, int rstep, int gstep)
{
  const int b = blockIdx.x, tid = threadIdx.x;
  float* cbuf = ws_f + CBUF_OFF;
  float* pmax = ws_f + PMAX_OFF;
  float* psum = ws_f + PSUM_OFF;
  int* pidx = ws_i;

  __shared__ float s_wm[4]; __shared__ int s_wi[4];
  __shared__ float s_ws[4];
  __shared__ int s_tok;
  __shared__ float s_emb[EMBSZ], s_h[HIDSZ], s_hnew[HIDSZ];
  __shared__ float s_hg[3 * HIDSZ], s_probs[TENCSZ];

  const int lane = tid & 63, wave = tid >> 6;

  if (rstep >= 0) {
    float m = -FLT_MAX; int mi = 0x7fffffff;
    for (int i = tid; i < NSLOT; i += 256) {
      float mm = pmax[b * NSLOT + i]; int ii = pidx[b * NSLOT + i];
      if (mm > m || (mm == m && ii < mi)) { m = mm; mi = ii; }
    }
#pragma unroll
    for (int off = 32; off; off >>= 1) {
      float om = __shfl_xor(m, off); int oi = __shfl_xor(mi, off);
      if (om > m || (om == m && oi < mi)) { m = om; mi = oi; }
    }
    if (lane == 0) { s_wm[wave] = m; s_wi[wave] = mi; }
    __syncthreads();
    float gm = s_wm[0]; int gi_ = s_wi[0];
#pragma unroll
    for (int q = 1; q < 4; ++q) {
      if (s_wm[q] > gm || (s_wm[q] == gm && s_wi[q] < gi_)) { gm = s_wm[q]; gi_ = s_wi[q]; }
    }
    float e = 0.f;
    for (int i = tid; i < NSLOT; i += 256)
      e += psum[b * NSLOT + i] * __expf(pmax[b * NSLOT + i] - gm);
#pragma unroll
    for (int off = 32; off; off >>= 1) e += __shfl_xor(e, off);
    if (lane == 0) s_ws[wave] = e;
    __syncthreads();
    if (tid == 0) {
      float tot = s_ws[0] + s_ws[1] + s_ws[2] + s_ws[3];
      cbuf[rstep * BSZ + b] = gm + logf(tot);
      out[(size_t)STEPSN * BSZ * VOCABSZ + rstep * BSZ + b] = (float)gi_;
      s_tok = gi_;
    }
    __syncthreads();
  }

  if (gstep >= 0) {
    const int tok = (gstep == 0) ? STARTTOK : s_tok;
    gru_attn(tid, b, tok, gstep, enc, inith, embed, W_ih, W_hh, b_ih, b_hh,
             ws_f, s_emb, s_h, s_hnew, s_hg, s_probs);
  }
}

// ---------------------------------------------------------------------------
// Last-step subtract: out[23,b,v] -= c[23,b].
// ---------------------------------------------------------------------------
__global__ __launch_bounds__(256) void sub_last_kernel(
    const float* __restrict__ cbuf, float* __restrict__ out)
{
  size_t i = ((size_t)blockIdx.x * 256 + threadIdx.x) * 8;
  if (i >= (size_t)BSZ * VOCABSZ) return;
  int b = (int)(i / VOCABSZ);
  float cv = cbuf[(STEPSN - 1) * BSZ + b];
  float4* p = (float4*)(out + (size_t)(STEPSN - 1) * BSZ * VOCABSZ + i);
  float4 x0 = p[0], x1 = p[1];
  x0.x -= cv; x0.y -= cv; x0.z -= cv; x0.w -= cv;
  x1.x -= cv; x1.y -= cv; x1.z -= cv; x1.w -= cv;
  p[0] = x0; p[1] = x1;
}

extern "C" void kernel_launch(void* const* d_in, const int* in_sizes, int n_in,
                              void* d_out, int out_size, void* d_ws, size_t ws_size,
                              hipStream_t stream)
{
  const float* enc   = (const float*)d_in[0];
  const float* inith = (const float*)d_in[1];
  const float* embed = (const float*)d_in[2];
  const float* W_ih  = (const float*)d_in[3];
  const float* W_hh  = (const float*)d_in[4];
  const float* b_ih  = (const float*)d_in[5];
  const float* b_hh  = (const float*)d_in[6];
  const float* Wl    = (const float*)d_in[7];
  const float* bl    = (const float*)d_in[8];
  float* out = (float*)d_out;

  float* ws_f = (float*)d_ws;
  int* ws_i = (int*)(ws_f + WS_FLOATS);

  rg_kernel<<<BSZ, 256, 0, stream>>>(enc, inith, embed, W_ih, W_hh, b_ih, b_hh,
                                     ws_f, ws_i, out, -1, 0);
  for (int t = 0; t < STEPSN; ++t) {
    step_kernel<<<NBLK, 256, 0, stream>>>(Wl, bl, ws_f, ws_f, ws_i, out, t);
    rg_kernel<<<BSZ, 256, 0, stream>>>(enc, inith, embed, W_ih, W_hh, b_ih, b_hh,
                                       ws_f, ws_i, out, t, (t < STEPSN - 1) ? (t + 1) : -1);
  }
  const int nsub = (BSZ * VOCABSZ / 8 + 255) / 256;
  sub_last_kernel<<<nsub, 256, 0, stream>>>(ws_f + CBUF_OFF, out);
}